// Round 6
// baseline (7338.705 us; speedup 1.0000x reference)
//
#include <hip/hip_runtime.h>
#include <hip/hip_fp16.h>

#define N0C 200000
#define N1C 600000
#define N2C 400000
#define NRC (N0C + N1C + N2C)
#define NGC 128
#define D 32
#define SCAN_TILE 2048
#define CHUNK_EDGES 16384
#define NBUK_MAX 1184

// act buffer row bases (rank-concatenated)
#define AB0 0
#define AB1 N0C
#define AB2 (N0C + N1C)

// ---------- input fp32 -> fp16 ----------
__global__ void tohalf_kernel(const float* __restrict__ x, __half* __restrict__ o, size_t n4) {
    size_t t = (size_t)blockIdx.x * blockDim.x + threadIdx.x;
    size_t stride = (size_t)gridDim.x * blockDim.x;
    for (size_t i = t; i < n4; i += stride) {
        float4 v = reinterpret_cast<const float4*>(x)[i];
        __half2 h01 = __floats2half2_rn(v.x, v.y);
        __half2 h23 = __floats2half2_rn(v.z, v.w);
        reinterpret_cast<__half2*>(o)[2 * i] = h01;
        reinterpret_cast<__half2*>(o)[2 * i + 1] = h23;
    }
}

// ---------- CSR row histogram + scan ----------
__global__ void hist_kernel(const int* __restrict__ rows, int* __restrict__ counts, int nnz) {
    int e = blockIdx.x * blockDim.x + threadIdx.x;
    if (e >= nnz) return;
    atomicAdd(&counts[rows[e]], 1);
}

__global__ void scan_phase1(const int* __restrict__ counts, int* __restrict__ bsums, int n) {
    __shared__ int sd[256];
    int base = blockIdx.x * SCAN_TILE;
    int s = 0;
    for (int i = threadIdx.x; i < SCAN_TILE; i += 256) {
        int idx = base + i;
        s += (idx < n) ? counts[idx] : 0;
    }
    sd[threadIdx.x] = s;
    __syncthreads();
    for (int o = 128; o > 0; o >>= 1) {
        if (threadIdx.x < o) sd[threadIdx.x] += sd[threadIdx.x + o];
        __syncthreads();
    }
    if (threadIdx.x == 0) bsums[blockIdx.x] = sd[0];
}

__global__ void scan_phase2(int* __restrict__ bsums, int nb) {
    __shared__ int sd[1024];
    for (int i = threadIdx.x; i < nb; i += 256) sd[i] = bsums[i];
    __syncthreads();
    if (threadIdx.x == 0) {
        int acc = 0;
        for (int i = 0; i < nb; ++i) { int v = sd[i]; sd[i] = acc; acc += v; }
        bsums[nb] = acc;
    }
    __syncthreads();
    for (int i = threadIdx.x; i < nb; i += 256) bsums[i] = sd[i];
}

// writes scanned array; cursor copy optional
__global__ void scan_phase3(const int* __restrict__ counts, const int* __restrict__ bsums,
                            int* __restrict__ rowptr, int* __restrict__ cursor, int n) {
    __shared__ int sd[256];
    int base = blockIdx.x * SCAN_TILE + threadIdx.x * 8;
    int v[8];
    int s = 0;
#pragma unroll
    for (int u = 0; u < 8; ++u) {
        int idx = base + u;
        int c = (idx < n) ? counts[idx] : 0;
        v[u] = s;
        s += c;
    }
    sd[threadIdx.x] = s;
    __syncthreads();
    if (threadIdx.x == 0) {
        int acc = bsums[blockIdx.x];
        for (int i = 0; i < 256; ++i) { int q = sd[i]; sd[i] = acc; acc += q; }
    }
    __syncthreads();
    int off = sd[threadIdx.x];
#pragma unroll
    for (int u = 0; u < 8; ++u) {
        int idx = base + u;
        if (idx < n) {
            int w = off + v[u];
            rowptr[idx] = w;
            if (cursor) cursor[idx] = w;
        }
    }
}

__global__ void set_total_kernel(int* __restrict__ dst, const int* __restrict__ src) {
    *dst = *src;
}

// ---------- binned scatter phase 1: per-chunk bucket histogram (transposed) ----------
__global__ __launch_bounds__(256) void bhist_kernel(const int* __restrict__ rows, int nnz,
                                                    int shift, int nbuk, int ncht, int chunk0,
                                                    int* __restrict__ HT) {
    __shared__ int h[NBUK_MAX];
    for (int i = threadIdx.x; i < nbuk; i += 256) h[i] = 0;
    __syncthreads();
    int base = blockIdx.x * CHUNK_EDGES;
    for (int i = threadIdx.x; i < CHUNK_EDGES; i += 256) {
        int e = base + i;
        if (e < nnz) atomicAdd(&h[rows[e] >> shift], 1);
    }
    __syncthreads();
    int c = chunk0 + blockIdx.x;
    for (int b = threadIdx.x; b < nbuk; b += 256) HT[b * ncht + c] = h[b];
}

// ---------- binned scatter phase 2: append into exclusive (bucket,chunk) stage ranges ----------
__global__ __launch_bounds__(256) void bin_kernel(const int* __restrict__ rows,
                                                  const int* __restrict__ cols,
                                                  const float* __restrict__ vals, int nnz,
                                                  int shift, int nbuk, int ncht, int chunk0,
                                                  int colbase, const int* __restrict__ HS,
                                                  int2* __restrict__ stage) {
    __shared__ int cur[NBUK_MAX];
    int c = chunk0 + blockIdx.x;
    for (int b = threadIdx.x; b < nbuk; b += 256) cur[b] = HS[b * ncht + c];
    __syncthreads();
    int base = blockIdx.x * CHUNK_EDGES;
    for (int i = threadIdx.x; i < CHUNK_EDGES; i += 256) {
        int e = base + i;
        if (e < nnz) {
            int r = rows[e];
            int b = r >> shift;
            int pos = atomicAdd(&cur[b], 1);
            int rl = r - (b << shift);
            stage[pos] = make_int2((rl << 22) | (cols[e] + colbase), __float_as_int(vals[e]));
        }
    }
}

__global__ void extract_b_kernel(const int* __restrict__ HS, int ncht, int nbuk, int total,
                                 int* __restrict__ B) {
    int b = blockIdx.x * blockDim.x + threadIdx.x;
    if (b < nbuk) B[b] = HS[b * ncht];
    if (b == nbuk) B[b] = total;
}

// ---------- binned scatter phase 3: one block per bucket -> final CSR order ----------
__global__ __launch_bounds__(256) void binscatter_kernel(const int2* __restrict__ stage,
                                                         const int* __restrict__ B, int shift,
                                                         int* __restrict__ cursor,
                                                         int2* __restrict__ cv) {
    int b = blockIdx.x;
    int s0 = B[b], s1 = B[b + 1];
    int rb = b << shift;
    for (int i = s0 + threadIdx.x; i < s1; i += 256) {
        int2 e = stage[i];
        int row = rb + (int)((unsigned)e.x >> 22);
        int col = e.x & 0x3FFFFF;
        int pos = atomicAdd(&cursor[row], 1);
        cv[pos] = make_int2(col, e.y);
    }
}

// ---------- projection: XWslot[row, 32] = x[row, :DIN] @ W ----------
template <int DIN>
__global__ __launch_bounds__(256) void xw_kernel(const __half* __restrict__ x,
                                                 const float* __restrict__ W,
                                                 __half* __restrict__ o, int n) {
    __shared__ float Ws[DIN * 32];
    for (int i = threadIdx.x; i < DIN * 32; i += 256) Ws[i] = W[i];
    __syncthreads();
    int g = (blockIdx.x * 256 + threadIdx.x) >> 5;
    int j = threadIdx.x & 31;
    int gstride = (gridDim.x * 256) >> 5;
    for (int row = g; row < n; row += gstride) {
        float xlo = __half2float(x[(size_t)row * DIN + j]);
        float xhi = 0.f;
        if (DIN == 64) xhi = __half2float(x[(size_t)row * DIN + 32 + j]);
        float s = 0.f;
#pragma unroll
        for (int k = 0; k < 32; ++k)
            s = fmaf(__shfl(xlo, k, 32), Ws[k * 32 + j], s);
        if (DIN == 64) {
#pragma unroll
            for (int k = 0; k < 32; ++k)
                s = fmaf(__shfl(xhi, k, 32), Ws[(32 + k) * 32 + j], s);
        }
        o[(size_t)row * 32 + j] = __float2half(s);
    }
}

// ---------- pure gather: act[rowbase+g, j] = relu(sum_k v_k * XW[c_k, j]) * scale ----------
__global__ __launch_bounds__(256, 8) void gather_kernel(
    const int* __restrict__ rp, const int2* __restrict__ cv,
    const __half* __restrict__ XW, __half* __restrict__ act,
    int rowbase, float scale, int n) {
    int g = (blockIdx.x * 256 + threadIdx.x) >> 5;
    int j = threadIdx.x & 31;
    if (g >= n) return;
    int ks = rp[g], ke = rp[g + 1];
    float s = 0.f;
    for (int k = ks; k < ke; k += 16) {
        int idx[16]; float vv[16];
#pragma unroll
        for (int u = 0; u < 16; ++u) {
            int kk = k + u;
            idx[u] = (kk < ke) ? kk : (ke - 1);   // clamped: always a valid edge
        }
        int2 e[16];
#pragma unroll
        for (int u = 0; u < 16; ++u) e[u] = cv[idx[u]];
        float xg[16];
#pragma unroll
        for (int u = 0; u < 16; ++u)
            xg[u] = __half2float(XW[(size_t)e[u].x * 32 + j]);
#pragma unroll
        for (int u = 0; u < 16; ++u) {
            vv[u] = (k + u < ke) ? __int_as_float(e[u].y) : 0.f;
            s = fmaf(vv[u], xg[u], s);
        }
    }
    act[(size_t)(rowbase + g) * 32 + j] = __float2half(fmaxf(s, 0.f) * scale);
}

// ---------- pooling (batch sorted) ----------
__global__ void pool_kernel(const __half* __restrict__ x1, const int* __restrict__ batch,
                            float* __restrict__ sums, float* __restrict__ cnt, int n) {
    const int RPG = 512;
    int j = threadIdx.x & 31;
    int s = threadIdx.x >> 5;
    long long start = ((long long)blockIdx.x * 8 + s) * RPG;
    if (start >= n) return;
    long long end = start + RPG;
    if (end > n) end = n;
    int curg = batch[start];
    float a = 0.f, c = 0.f;
    for (long long r = start; r < end; ++r) {
        int g = batch[r];
        if (g != curg) {
            atomicAdd(&sums[(size_t)curg * D + j], a);
            if (j == 0) atomicAdd(&cnt[curg], c);
            a = 0.f; c = 0.f; curg = g;
        }
        a += fabsf(__half2float(x1[(size_t)r * D + j]));
        c += 1.f;
    }
    atomicAdd(&sums[(size_t)curg * D + j], a);
    if (j == 0) atomicAdd(&cnt[curg], c);
}

// ---------- head ----------
__global__ void head_kernel(const float* __restrict__ sums, const float* __restrict__ cnt,
                            const float* __restrict__ w1, const float* __restrict__ b1,
                            const float* __restrict__ w2, const float* __restrict__ b2,
                            float* __restrict__ out) {
    __shared__ float W1s[D * D], W2s[D * 10], B1s[D], B2s[10];
    int tid = threadIdx.x;
    for (int i = tid; i < D * D; i += blockDim.x) W1s[i] = w1[i];
    for (int i = tid; i < D * 10; i += blockDim.x) W2s[i] = w2[i];
    if (tid < D) B1s[tid] = b1[tid];
    if (tid < 10) B2s[tid] = b2[tid];
    __syncthreads();
    int g = tid;
    if (g >= NGC) return;
    float invc = 1.f / fmaxf(cnt[g], 1.f);
    float p[D];
#pragma unroll
    for (int k = 0; k < D; ++k) p[k] = sums[(size_t)g * D + k] * invc;
    float h[D];
#pragma unroll
    for (int j = 0; j < D; ++j) {
        float s = B1s[j];
#pragma unroll
        for (int k = 0; k < D; ++k) s = fmaf(p[k], W1s[k * D + j], s);
        h[j] = fmaxf(s, 0.f);
    }
    float l[10];
    float m = -1e30f;
#pragma unroll
    for (int o = 0; o < 10; ++o) {
        float s = B2s[o];
#pragma unroll
        for (int k = 0; k < D; ++k) s = fmaf(h[k], W2s[k * 10 + o], s);
        l[o] = s;
        m = fmaxf(m, s);
    }
    float den = 0.f;
#pragma unroll
    for (int o = 0; o < 10; ++o) { l[o] = expf(l[o] - m); den += l[o]; }
    float inv = 1.f / den;
#pragma unroll
    for (int o = 0; o < 10; ++o) out[g * 10 + o] = l[o] * inv;
}

extern "C" void kernel_launch(void* const* d_in, const int* in_sizes, int n_in,
                              void* d_out, int out_size, void* d_ws, size_t ws_size,
                              hipStream_t stream) {
    const float* X0 = (const float*)d_in[0];
    const float* X1 = (const float*)d_in[1];
    const float* X2 = (const float*)d_in[2];
    // mats: 0=L0,1=L1,2=L2,3=B2D3,4=D2B1TD1inv,5=D1invB1,6=B2TD2inv
    const int* spr[7]; const int* spc[7]; const float* spv[7]; int spn[7];
    for (int m = 0; m < 7; ++m) {
        spr[m] = (const int*)d_in[3 + m * 3];
        spc[m] = (const int*)d_in[4 + m * 3];
        spv[m] = (const float*)d_in[5 + m * 3];
        spn[m] = in_sizes[3 + m * 3];
    }
    const int* batch1 = (const int*)d_in[24];
    const float* W1 = (const float*)d_in[25];
    const float* W234 = (const float*)d_in[26];
    const float* mlp1_w = (const float*)d_in[27];
    const float* mlp1_b = (const float*)d_in[28];
    const float* mlp2_w = (const float*)d_in[29];
    const float* mlp2_b = (const float*)d_in[30];
    float* out = (float*)d_out;

    // per-mat: source act base (rank concat), W index, src rows
    const int srcbase_mat[7] = { AB0, AB1, AB2, AB2, AB0, AB1, AB1 };
    const int srcrows_mat[7] = { N0C, N1C, N2C, N2C, N0C, N1C, N1C };
    const int wk_mat[7]      = { 0, 2, 6, 5, 1, 3, 4 };
    int XB[7];  // XWbuf slot bases
    {
        int acc = 0;
        for (int m = 0; m < 7; ++m) { XB[m] = acc; acc += srcrows_mat[m]; }
    }
    const int XWROWS = 3000000;

    // rank CSRs: rank0 <- {L0, D1invB1}; rank1 <- {D2B1TD1inv, L1, B2D3}; rank2 <- {B2TD2inv, L2}
    struct RankDef { int nrows; int nmats; int mats[3]; int shift; };
    const RankDef rdefs[3] = {
        { N0C, 2, { 0, 5, -1 }, 8 },   // 782 buckets of 256 rows
        { N1C, 3, { 4, 1, 3 }, 9 },    // 1172 buckets of 512 rows
        { N2C, 2, { 6, 2, -1 }, 9 },   // 782 buckets of 512 rows
    };

    // ---- workspace carve ----
    char* wp = (char*)d_ws;
    __half* Xh64 = (__half*)wp;            wp += (size_t)NRC * 64 * sizeof(__half);   // 153.6MB
    __half* act = (__half*)wp;             wp += (size_t)NRC * 32 * sizeof(__half);   // 76.8MB
    __half* XWbuf = (__half*)wp;           wp += (size_t)XWROWS * 32 * sizeof(__half);// 192MB
    size_t total_nnz = 0;
    for (int m = 0; m < 7; ++m) total_nnz += (size_t)spn[m];
    int2* cv_base = (int2*)wp;             wp += total_nnz * sizeof(int2);            // 134.4MB
    int* rowptr_base = (int*)wp;           wp += (size_t)(NRC + 3) * sizeof(int);
    int* counts = (int*)wp;                wp += (size_t)N1C * sizeof(int);
    int* cursor = (int*)wp;                wp += (size_t)N1C * sizeof(int);
    int* HT = (int*)wp;                    wp += (size_t)1000000 * sizeof(int);
    int* HS = (int*)wp;                    wp += (size_t)1000000 * sizeof(int);
    int* Bb = (int*)wp;                    wp += (size_t)(NBUK_MAX + 1) * sizeof(int);
    int* bsums = (int*)wp;                 wp += 1040 * sizeof(int);
    float* sums = (float*)wp;              wp += (size_t)NGC * D * sizeof(float);
    float* cnt = (float*)wp;               wp += (size_t)NGC * sizeof(float);

    // stage aliases XWbuf (build finishes before first xw write)
    int2* stage = (int2*)XWbuf;

    // ---- inputs -> fp16 (concatenated [X0;X1;X2], stride 64) ----
    tohalf_kernel<<<2048, 256, 0, stream>>>(X0, Xh64 + (size_t)AB0 * 64, (size_t)N0C * 16);
    tohalf_kernel<<<2048, 256, 0, stream>>>(X1, Xh64 + (size_t)AB1 * 64, (size_t)N1C * 16);
    tohalf_kernel<<<2048, 256, 0, stream>>>(X2, Xh64 + (size_t)AB2 * 64, (size_t)N2C * 16);

    // ---- build 3 merged rank CSRs via binned scatter ----
    int* rp_r[3]; int2* cv_r[3];
    {
        size_t rpoff = 0, cvoff = 0;
        for (int r = 0; r < 3; ++r) {
            const RankDef& rd = rdefs[r];
            int nr = rd.nrows;
            int shift = rd.shift;
            int nbuk = (nr + (1 << shift) - 1) >> shift;
            rp_r[r] = rowptr_base + rpoff; rpoff += (size_t)nr + 1;
            cv_r[r] = cv_base + cvoff;
            int rank_nnz = 0;
            int ncht = 0;
            int chunk0_mat[3] = { 0, 0, 0 };
            for (int i = 0; i < rd.nmats; ++i) {
                chunk0_mat[i] = ncht;
                ncht += (spn[rd.mats[i]] + CHUNK_EDGES - 1) / CHUNK_EDGES;
                rank_nnz += spn[rd.mats[i]];
            }

            // per-row counts -> rowptr + cursor
            int nb = (nr + SCAN_TILE - 1) / SCAN_TILE;
            hipMemsetAsync(counts, 0, (size_t)nr * sizeof(int), stream);
            for (int i = 0; i < rd.nmats; ++i) {
                int m = rd.mats[i];
                hist_kernel<<<(spn[m] + 255) / 256, 256, 0, stream>>>(spr[m], counts, spn[m]);
            }
            scan_phase1<<<nb, 256, 0, stream>>>(counts, bsums, nr);
            scan_phase2<<<1, 256, 0, stream>>>(bsums, nb);
            scan_phase3<<<nb, 256, 0, stream>>>(counts, bsums, rp_r[r], cursor, nr);
            set_total_kernel<<<1, 1, 0, stream>>>(rp_r[r] + nr, bsums + nb);

            // (bucket, chunk) histogram -> scan -> stage offsets
            for (int i = 0; i < rd.nmats; ++i) {
                int m = rd.mats[i];
                int gch = (spn[m] + CHUNK_EDGES - 1) / CHUNK_EDGES;
                bhist_kernel<<<gch, 256, 0, stream>>>(spr[m], spn[m], shift, nbuk, ncht,
                                                      chunk0_mat[i], HT);
            }
            int nht = nbuk * ncht;
            int nbh = (nht + SCAN_TILE - 1) / SCAN_TILE;
            scan_phase1<<<nbh, 256, 0, stream>>>(HT, bsums, nht);
            scan_phase2<<<1, 256, 0, stream>>>(bsums, nbh);
            scan_phase3<<<nbh, 256, 0, stream>>>(HT, bsums, HS, nullptr, nht);
            extract_b_kernel<<<(nbuk + 256) / 256, 256, 0, stream>>>(HS, ncht, nbuk,
                                                                     rank_nnz, Bb);

            // bin into stage, then finalize per bucket
            for (int i = 0; i < rd.nmats; ++i) {
                int m = rd.mats[i];
                int gch = (spn[m] + CHUNK_EDGES - 1) / CHUNK_EDGES;
                bin_kernel<<<gch, 256, 0, stream>>>(spr[m], spc[m], spv[m], spn[m], shift,
                                                    nbuk, ncht, chunk0_mat[i], XB[m], HS, stage);
            }
            binscatter_kernel<<<nbuk, 256, 0, stream>>>(stage, Bb, shift, cursor, cv_r[r]);

            cvoff += (size_t)rank_nnz;
        }
    }

    // ---- 4 layers: 7 projections + 3 gathers each ----
    for (int l = 0; l < 4; ++l) {
        const float* Wl = (l == 0) ? W1 : W234 + (size_t)(l - 1) * 7 * 32 * 32;
        const size_t wst = (l == 0) ? (size_t)64 * 32 : (size_t)32 * 32;
        for (int m = 0; m < 7; ++m) {
            const float* Wm = Wl + (size_t)wk_mat[m] * wst;
            __half* o = XWbuf + (size_t)XB[m] * 32;
            int n = srcrows_mat[m];
            if (l == 0) {
                const __half* x = Xh64 + (size_t)srcbase_mat[m] * 64;
                xw_kernel<64><<<4096, 256, 0, stream>>>(x, Wm, o, n);
            } else {
                const __half* x = act + (size_t)srcbase_mat[m] * 32;
                xw_kernel<32><<<4096, 256, 0, stream>>>(x, Wm, o, n);
            }
        }
        gather_kernel<<<(int)(((size_t)N0C * 32 + 255) / 256), 256, 0, stream>>>(
            rp_r[0], cv_r[0], XWbuf, act, AB0, 0.5f, N0C);
        gather_kernel<<<(int)(((size_t)N1C * 32 + 255) / 256), 256, 0, stream>>>(
            rp_r[1], cv_r[1], XWbuf, act, AB1, 1.f / 3.f, N1C);
        gather_kernel<<<(int)(((size_t)N2C * 32 + 255) / 256), 256, 0, stream>>>(
            rp_r[2], cv_r[2], XWbuf, act, AB2, 0.5f, N2C);
    }

    hipMemsetAsync(sums, 0, (size_t)(NGC * D + NGC) * sizeof(float), stream);
    {
        int groups = (N1C + 511) / 512;
        int blocks = (groups + 7) / 8;
        pool_kernel<<<blocks, 256, 0, stream>>>(act + (size_t)AB1 * 32, batch1, sums, cnt, N1C);
    }
    head_kernel<<<1, 128, 0, stream>>>(sums, cnt, mlp1_w, mlp1_b, mlp2_w, mlp2_b, out);
}

// Round 7
// 3959.010 us; speedup vs baseline: 1.8537x; 1.8537x over previous
//
#include <hip/hip_runtime.h>
#include <hip/hip_fp16.h>

#define N0C 200000
#define N1C 600000
#define N2C 400000
#define NRC (N0C + N1C + N2C)
#define NGC 128
#define D 32
#define SCAN_TILE 2048
#define CHUNK_EDGES 16384
#define NBUK_MAX 1184

// act buffer row bases (rank-concatenated)
#define AB0 0
#define AB1 N0C
#define AB2 (N0C + N1C)

typedef __attribute__((ext_vector_type(8))) _Float16 half8;
typedef __attribute__((ext_vector_type(4))) float f32x4;

// ---------- input fp32 -> fp16 ----------
__global__ void tohalf_kernel(const float* __restrict__ x, __half* __restrict__ o, size_t n4) {
    size_t t = (size_t)blockIdx.x * blockDim.x + threadIdx.x;
    size_t stride = (size_t)gridDim.x * blockDim.x;
    for (size_t i = t; i < n4; i += stride) {
        float4 v = reinterpret_cast<const float4*>(x)[i];
        __half2 h01 = __floats2half2_rn(v.x, v.y);
        __half2 h23 = __floats2half2_rn(v.z, v.w);
        reinterpret_cast<__half2*>(o)[2 * i] = h01;
        reinterpret_cast<__half2*>(o)[2 * i + 1] = h23;
    }
}

// ---------- CSR row histogram + scan ----------
__global__ void hist_kernel(const int* __restrict__ rows, int* __restrict__ counts, int nnz) {
    int e = blockIdx.x * blockDim.x + threadIdx.x;
    if (e >= nnz) return;
    atomicAdd(&counts[rows[e]], 1);
}

__global__ void scan_phase1(const int* __restrict__ counts, int* __restrict__ bsums, int n) {
    __shared__ int sd[256];
    int base = blockIdx.x * SCAN_TILE;
    int s = 0;
    for (int i = threadIdx.x; i < SCAN_TILE; i += 256) {
        int idx = base + i;
        s += (idx < n) ? counts[idx] : 0;
    }
    sd[threadIdx.x] = s;
    __syncthreads();
    for (int o = 128; o > 0; o >>= 1) {
        if (threadIdx.x < o) sd[threadIdx.x] += sd[threadIdx.x + o];
        __syncthreads();
    }
    if (threadIdx.x == 0) bsums[blockIdx.x] = sd[0];
}

__global__ void scan_phase2(int* __restrict__ bsums, int nb) {
    __shared__ int sd[1024];
    for (int i = threadIdx.x; i < nb; i += 256) sd[i] = bsums[i];
    __syncthreads();
    if (threadIdx.x == 0) {
        int acc = 0;
        for (int i = 0; i < nb; ++i) { int v = sd[i]; sd[i] = acc; acc += v; }
        bsums[nb] = acc;
    }
    __syncthreads();
    for (int i = threadIdx.x; i < nb; i += 256) bsums[i] = sd[i];
}

// writes scanned array; cursor copy optional
__global__ void scan_phase3(const int* __restrict__ counts, const int* __restrict__ bsums,
                            int* __restrict__ rowptr, int* __restrict__ cursor, int n) {
    __shared__ int sd[256];
    int base = blockIdx.x * SCAN_TILE + threadIdx.x * 8;
    int v[8];
    int s = 0;
#pragma unroll
    for (int u = 0; u < 8; ++u) {
        int idx = base + u;
        int c = (idx < n) ? counts[idx] : 0;
        v[u] = s;
        s += c;
    }
    sd[threadIdx.x] = s;
    __syncthreads();
    if (threadIdx.x == 0) {
        int acc = bsums[blockIdx.x];
        for (int i = 0; i < 256; ++i) { int q = sd[i]; sd[i] = acc; acc += q; }
    }
    __syncthreads();
    int off = sd[threadIdx.x];
#pragma unroll
    for (int u = 0; u < 8; ++u) {
        int idx = base + u;
        if (idx < n) {
            int w = off + v[u];
            rowptr[idx] = w;
            if (cursor) cursor[idx] = w;
        }
    }
}

__global__ void set_total_kernel(int* __restrict__ dst, const int* __restrict__ src) {
    *dst = *src;
}

// ---------- binned scatter phase 1: per-chunk bucket histogram (transposed) ----------
__global__ __launch_bounds__(256) void bhist_kernel(const int* __restrict__ rows, int nnz,
                                                    int shift, int nbuk, int ncht, int chunk0,
                                                    int* __restrict__ HT) {
    __shared__ int h[NBUK_MAX];
    for (int i = threadIdx.x; i < nbuk; i += 256) h[i] = 0;
    __syncthreads();
    int base = blockIdx.x * CHUNK_EDGES;
    for (int i = threadIdx.x; i < CHUNK_EDGES; i += 256) {
        int e = base + i;
        if (e < nnz) atomicAdd(&h[rows[e] >> shift], 1);
    }
    __syncthreads();
    int c = chunk0 + blockIdx.x;
    for (int b = threadIdx.x; b < nbuk; b += 256) HT[b * ncht + c] = h[b];
}

// ---------- binned scatter phase 2: append into exclusive (bucket,chunk) stage ranges ----------
__global__ __launch_bounds__(256) void bin_kernel(const int* __restrict__ rows,
                                                  const int* __restrict__ cols,
                                                  const float* __restrict__ vals, int nnz,
                                                  int shift, int nbuk, int ncht, int chunk0,
                                                  int colbase, const int* __restrict__ HS,
                                                  int2* __restrict__ stage) {
    __shared__ int cur[NBUK_MAX];
    int c = chunk0 + blockIdx.x;
    for (int b = threadIdx.x; b < nbuk; b += 256) cur[b] = HS[b * ncht + c];
    __syncthreads();
    int base = blockIdx.x * CHUNK_EDGES;
    for (int i = threadIdx.x; i < CHUNK_EDGES; i += 256) {
        int e = base + i;
        if (e < nnz) {
            int r = rows[e];
            int b = r >> shift;
            int pos = atomicAdd(&cur[b], 1);
            int rl = r - (b << shift);
            stage[pos] = make_int2((rl << 22) | (cols[e] + colbase), __float_as_int(vals[e]));
        }
    }
}

__global__ void extract_b_kernel(const int* __restrict__ HS, int ncht, int nbuk, int total,
                                 int* __restrict__ B) {
    int b = blockIdx.x * blockDim.x + threadIdx.x;
    if (b < nbuk) B[b] = HS[b * ncht];
    if (b == nbuk) B[b] = total;
}

// ---------- binned scatter phase 3: one block per bucket -> final CSR order ----------
__global__ __launch_bounds__(256) void binscatter_kernel(const int2* __restrict__ stage,
                                                         const int* __restrict__ B, int shift,
                                                         int* __restrict__ cursor,
                                                         int2* __restrict__ cv) {
    int b = blockIdx.x;
    int s0 = B[b], s1 = B[b + 1];
    int rb = b << shift;
    for (int i = s0 + threadIdx.x; i < s1; i += 256) {
        int2 e = stage[i];
        int row = rb + (int)((unsigned)e.x >> 22);
        int col = e.x & 0x3FFFFF;
        int pos = atomicAdd(&cursor[row], 1);
        cv[pos] = make_int2(col, e.y);
    }
}

// ---------- MFMA projection: XWslot[row, 32] = x[row, :DIN] @ W ----------
// A frag (16x32 fp16): lane l -> row (l&15), k = (l>>4)*8 + r  (contiguous 16B)
// B frag (32x16 fp16): lane l -> col (l&15), k = (l>>4)*8 + r
// D frag (16x16 f32):  lane l -> col (l&15), row = (l>>4)*4 + r
template <int DIN>
__global__ __launch_bounds__(256) void xw_mfma_kernel(const __half* __restrict__ x,
                                                      const float* __restrict__ W,
                                                      __half* __restrict__ o, int n) {
    int wave = (blockIdx.x * 256 + threadIdx.x) >> 6;
    int lane = threadIdx.x & 63;
    int nwaves = (gridDim.x * 256) >> 6;
    int li = lane & 15;
    int lk = lane >> 4;
    half8 bfrag[2][DIN / 32];
#pragma unroll
    for (int ct = 0; ct < 2; ++ct)
#pragma unroll
        for (int ks = 0; ks < DIN / 32; ++ks)
#pragma unroll
            for (int r = 0; r < 8; ++r) {
                int k = ks * 32 + lk * 8 + r;
                int j = ct * 16 + li;
                bfrag[ct][ks][r] = (_Float16)W[k * 32 + j];
            }
    int ntiles = (n + 15) >> 4;
    for (int t = wave; t < ntiles; t += nwaves) {
        int rbase = t << 4;
        int arow = rbase + li;
        int arowc = (arow < n) ? arow : (n - 1);
        half8 afrag[DIN / 32];
#pragma unroll
        for (int ks = 0; ks < DIN / 32; ++ks)
            afrag[ks] = *(const half8*)(x + (size_t)arowc * DIN + ks * 32 + lk * 8);
#pragma unroll
        for (int ct = 0; ct < 2; ++ct) {
            f32x4 acc = {0.f, 0.f, 0.f, 0.f};
#pragma unroll
            for (int ks = 0; ks < DIN / 32; ++ks)
                acc = __builtin_amdgcn_mfma_f32_16x16x32_f16(afrag[ks], bfrag[ct][ks], acc,
                                                             0, 0, 0);
#pragma unroll
            for (int r = 0; r < 4; ++r) {
                int row = rbase + lk * 4 + r;
                if (row < n)
                    o[(size_t)row * 32 + ct * 16 + li] = __float2half(acc[r]);
            }
        }
    }
}

// ---------- pure gather: 8 lanes per row, half4 per lane ----------
__global__ __launch_bounds__(256, 8) void gather_kernel(
    const int* __restrict__ rp, const int2* __restrict__ cv,
    const __half* __restrict__ XW, __half* __restrict__ act,
    int rowbase, float scale, int n) {
    int g = (blockIdx.x * 256 + threadIdx.x) >> 3;
    int j = threadIdx.x & 7;
    if (g >= n) return;
    int ks = rp[g], ke = rp[g + 1];
    float s0 = 0.f, s1 = 0.f, s2 = 0.f, s3 = 0.f;
    for (int k = ks; k < ke; k += 8) {
        int2 e[8];
#pragma unroll
        for (int u = 0; u < 8; ++u) {
            int kk = k + u;
            e[u] = cv[(kk < ke) ? kk : (ke - 1)];
        }
        uint2 q[8];
#pragma unroll
        for (int u = 0; u < 8; ++u)
            q[u] = *(const uint2*)(XW + (size_t)e[u].x * 32 + j * 4);
#pragma unroll
        for (int u = 0; u < 8; ++u) {
            float v = (k + u < ke) ? __int_as_float(e[u].y) : 0.f;
            __half2 h01 = *(__half2*)&q[u].x;
            __half2 h23 = *(__half2*)&q[u].y;
            float2 f01 = __half22float2(h01);
            float2 f23 = __half22float2(h23);
            s0 = fmaf(v, f01.x, s0);
            s1 = fmaf(v, f01.y, s1);
            s2 = fmaf(v, f23.x, s2);
            s3 = fmaf(v, f23.y, s3);
        }
    }
    __half2 o01 = __floats2half2_rn(fmaxf(s0, 0.f) * scale, fmaxf(s1, 0.f) * scale);
    __half2 o23 = __floats2half2_rn(fmaxf(s2, 0.f) * scale, fmaxf(s3, 0.f) * scale);
    uint2 ov;
    ov.x = *(unsigned*)&o01;
    ov.y = *(unsigned*)&o23;
    *(uint2*)(act + (size_t)(rowbase + g) * 32 + j * 4) = ov;
}

// ---------- pooling (batch sorted) ----------
__global__ void pool_kernel(const __half* __restrict__ x1, const int* __restrict__ batch,
                            float* __restrict__ sums, float* __restrict__ cnt, int n) {
    const int RPG = 512;
    int j = threadIdx.x & 31;
    int s = threadIdx.x >> 5;
    long long start = ((long long)blockIdx.x * 8 + s) * RPG;
    if (start >= n) return;
    long long end = start + RPG;
    if (end > n) end = n;
    int curg = batch[start];
    float a = 0.f, c = 0.f;
    for (long long r = start; r < end; ++r) {
        int g = batch[r];
        if (g != curg) {
            atomicAdd(&sums[(size_t)curg * D + j], a);
            if (j == 0) atomicAdd(&cnt[curg], c);
            a = 0.f; c = 0.f; curg = g;
        }
        a += fabsf(__half2float(x1[(size_t)r * D + j]));
        c += 1.f;
    }
    atomicAdd(&sums[(size_t)curg * D + j], a);
    if (j == 0) atomicAdd(&cnt[curg], c);
}

// ---------- head ----------
__global__ void head_kernel(const float* __restrict__ sums, const float* __restrict__ cnt,
                            const float* __restrict__ w1, const float* __restrict__ b1,
                            const float* __restrict__ w2, const float* __restrict__ b2,
                            float* __restrict__ out) {
    __shared__ float W1s[D * D], W2s[D * 10], B1s[D], B2s[10];
    int tid = threadIdx.x;
    for (int i = tid; i < D * D; i += blockDim.x) W1s[i] = w1[i];
    for (int i = tid; i < D * 10; i += blockDim.x) W2s[i] = w2[i];
    if (tid < D) B1s[tid] = b1[tid];
    if (tid < 10) B2s[tid] = b2[tid];
    __syncthreads();
    int g = tid;
    if (g >= NGC) return;
    float invc = 1.f / fmaxf(cnt[g], 1.f);
    float p[D];
#pragma unroll
    for (int k = 0; k < D; ++k) p[k] = sums[(size_t)g * D + k] * invc;
    float h[D];
#pragma unroll
    for (int j = 0; j < D; ++j) {
        float s = B1s[j];
#pragma unroll
        for (int k = 0; k < D; ++k) s = fmaf(p[k], W1s[k * D + j], s);
        h[j] = fmaxf(s, 0.f);
    }
    float l[10];
    float m = -1e30f;
#pragma unroll
    for (int o = 0; o < 10; ++o) {
        float s = B2s[o];
#pragma unroll
        for (int k = 0; k < D; ++k) s = fmaf(h[k], W2s[k * 10 + o], s);
        l[o] = s;
        m = fmaxf(m, s);
    }
    float den = 0.f;
#pragma unroll
    for (int o = 0; o < 10; ++o) { l[o] = expf(l[o] - m); den += l[o]; }
    float inv = 1.f / den;
#pragma unroll
    for (int o = 0; o < 10; ++o) out[g * 10 + o] = l[o] * inv;
}

extern "C" void kernel_launch(void* const* d_in, const int* in_sizes, int n_in,
                              void* d_out, int out_size, void* d_ws, size_t ws_size,
                              hipStream_t stream) {
    const float* X0 = (const float*)d_in[0];
    const float* X1 = (const float*)d_in[1];
    const float* X2 = (const float*)d_in[2];
    // mats: 0=L0,1=L1,2=L2,3=B2D3,4=D2B1TD1inv,5=D1invB1,6=B2TD2inv
    const int* spr[7]; const int* spc[7]; const float* spv[7]; int spn[7];
    for (int m = 0; m < 7; ++m) {
        spr[m] = (const int*)d_in[3 + m * 3];
        spc[m] = (const int*)d_in[4 + m * 3];
        spv[m] = (const float*)d_in[5 + m * 3];
        spn[m] = in_sizes[3 + m * 3];
    }
    const int* batch1 = (const int*)d_in[24];
    const float* W1 = (const float*)d_in[25];
    const float* W234 = (const float*)d_in[26];
    const float* mlp1_w = (const float*)d_in[27];
    const float* mlp1_b = (const float*)d_in[28];
    const float* mlp2_w = (const float*)d_in[29];
    const float* mlp2_b = (const float*)d_in[30];
    float* out = (float*)d_out;

    // per-mat: source act base (rank concat), W index, src rows
    const int srcbase_mat[7] = { AB0, AB1, AB2, AB2, AB0, AB1, AB1 };
    const int srcrows_mat[7] = { N0C, N1C, N2C, N2C, N0C, N1C, N1C };
    const int wk_mat[7]      = { 0, 2, 6, 5, 1, 3, 4 };
    int XB[7];  // XWbuf slot bases
    {
        int acc = 0;
        for (int m = 0; m < 7; ++m) { XB[m] = acc; acc += srcrows_mat[m]; }
    }
    const int XWROWS = 3000000;

    // rank CSRs: rank0 <- {L0, D1invB1}; rank1 <- {D2B1TD1inv, L1, B2D3}; rank2 <- {B2TD2inv, L2}
    struct RankDef { int nrows; int nmats; int mats[3]; int shift; };
    const RankDef rdefs[3] = {
        { N0C, 2, { 0, 5, -1 }, 8 },
        { N1C, 3, { 4, 1, 3 }, 9 },
        { N2C, 2, { 6, 2, -1 }, 9 },
    };

    // ---- workspace carve ----
    char* wp = (char*)d_ws;
    __half* Xh64 = (__half*)wp;            wp += (size_t)NRC * 64 * sizeof(__half);
    __half* act = (__half*)wp;             wp += (size_t)NRC * 32 * sizeof(__half);
    __half* XWbuf = (__half*)wp;           wp += (size_t)XWROWS * 32 * sizeof(__half);
    size_t total_nnz = 0;
    for (int m = 0; m < 7; ++m) total_nnz += (size_t)spn[m];
    int2* cv_base = (int2*)wp;             wp += total_nnz * sizeof(int2);
    int* rowptr_base = (int*)wp;           wp += (size_t)(NRC + 3) * sizeof(int);
    int* counts = (int*)wp;                wp += (size_t)N1C * sizeof(int);
    int* cursor = (int*)wp;                wp += (size_t)N1C * sizeof(int);
    int* HT = (int*)wp;                    wp += (size_t)1000000 * sizeof(int);
    int* HS = (int*)wp;                    wp += (size_t)1000000 * sizeof(int);
    int* Bb = (int*)wp;                    wp += (size_t)(NBUK_MAX + 1) * sizeof(int);
    int* bsums = (int*)wp;                 wp += 1040 * sizeof(int);
    float* sums = (float*)wp;              wp += (size_t)NGC * D * sizeof(float);
    float* cnt = (float*)wp;               wp += (size_t)NGC * sizeof(float);

    // stage aliases XWbuf (build finishes before first xw write)
    int2* stage = (int2*)XWbuf;

    // ---- inputs -> fp16 (concatenated [X0;X1;X2], stride 64) ----
    tohalf_kernel<<<2048, 256, 0, stream>>>(X0, Xh64 + (size_t)AB0 * 64, (size_t)N0C * 16);
    tohalf_kernel<<<2048, 256, 0, stream>>>(X1, Xh64 + (size_t)AB1 * 64, (size_t)N1C * 16);
    tohalf_kernel<<<2048, 256, 0, stream>>>(X2, Xh64 + (size_t)AB2 * 64, (size_t)N2C * 16);

    // ---- build 3 merged rank CSRs via binned scatter ----
    int* rp_r[3]; int2* cv_r[3];
    {
        size_t rpoff = 0, cvoff = 0;
        for (int r = 0; r < 3; ++r) {
            const RankDef& rd = rdefs[r];
            int nr = rd.nrows;
            int shift = rd.shift;
            int nbuk = (nr + (1 << shift) - 1) >> shift;
            rp_r[r] = rowptr_base + rpoff; rpoff += (size_t)nr + 1;
            cv_r[r] = cv_base + cvoff;
            int rank_nnz = 0;
            int ncht = 0;
            int chunk0_mat[3] = { 0, 0, 0 };
            for (int i = 0; i < rd.nmats; ++i) {
                chunk0_mat[i] = ncht;
                ncht += (spn[rd.mats[i]] + CHUNK_EDGES - 1) / CHUNK_EDGES;
                rank_nnz += spn[rd.mats[i]];
            }

            int nb = (nr + SCAN_TILE - 1) / SCAN_TILE;
            hipMemsetAsync(counts, 0, (size_t)nr * sizeof(int), stream);
            for (int i = 0; i < rd.nmats; ++i) {
                int m = rd.mats[i];
                hist_kernel<<<(spn[m] + 255) / 256, 256, 0, stream>>>(spr[m], counts, spn[m]);
            }
            scan_phase1<<<nb, 256, 0, stream>>>(counts, bsums, nr);
            scan_phase2<<<1, 256, 0, stream>>>(bsums, nb);
            scan_phase3<<<nb, 256, 0, stream>>>(counts, bsums, rp_r[r], cursor, nr);
            set_total_kernel<<<1, 1, 0, stream>>>(rp_r[r] + nr, bsums + nb);

            for (int i = 0; i < rd.nmats; ++i) {
                int m = rd.mats[i];
                int gch = (spn[m] + CHUNK_EDGES - 1) / CHUNK_EDGES;
                bhist_kernel<<<gch, 256, 0, stream>>>(spr[m], spn[m], shift, nbuk, ncht,
                                                      chunk0_mat[i], HT);
            }
            int nht = nbuk * ncht;
            int nbh = (nht + SCAN_TILE - 1) / SCAN_TILE;
            scan_phase1<<<nbh, 256, 0, stream>>>(HT, bsums, nht);
            scan_phase2<<<1, 256, 0, stream>>>(bsums, nbh);
            scan_phase3<<<nbh, 256, 0, stream>>>(HT, bsums, HS, nullptr, nht);
            extract_b_kernel<<<(nbuk + 256) / 256, 256, 0, stream>>>(HS, ncht, nbuk,
                                                                     rank_nnz, Bb);

            for (int i = 0; i < rd.nmats; ++i) {
                int m = rd.mats[i];
                int gch = (spn[m] + CHUNK_EDGES - 1) / CHUNK_EDGES;
                bin_kernel<<<gch, 256, 0, stream>>>(spr[m], spc[m], spv[m], spn[m], shift,
                                                    nbuk, ncht, chunk0_mat[i], XB[m], HS, stage);
            }
            binscatter_kernel<<<nbuk, 256, 0, stream>>>(stage, Bb, shift, cursor, cv_r[r]);

            cvoff += (size_t)rank_nnz;
        }
    }

    // ---- 4 layers: 7 MFMA projections + 3 gathers each ----
    for (int l = 0; l < 4; ++l) {
        const float* Wl = (l == 0) ? W1 : W234 + (size_t)(l - 1) * 7 * 32 * 32;
        const size_t wst = (l == 0) ? (size_t)64 * 32 : (size_t)32 * 32;
        for (int m = 0; m < 7; ++m) {
            const float* Wm = Wl + (size_t)wk_mat[m] * wst;
            __half* o = XWbuf + (size_t)XB[m] * 32;
            int n = srcrows_mat[m];
            if (l == 0) {
                const __half* x = Xh64 + (size_t)srcbase_mat[m] * 64;
                xw_mfma_kernel<64><<<2048, 256, 0, stream>>>(x, Wm, o, n);
            } else {
                const __half* x = act + (size_t)srcbase_mat[m] * 32;
                xw_mfma_kernel<32><<<2048, 256, 0, stream>>>(x, Wm, o, n);
            }
        }
        gather_kernel<<<(int)(((size_t)N0C * 8 + 255) / 256), 256, 0, stream>>>(
            rp_r[0], cv_r[0], XWbuf, act, AB0, 0.5f, N0C);
        gather_kernel<<<(int)(((size_t)N1C * 8 + 255) / 256), 256, 0, stream>>>(
            rp_r[1], cv_r[1], XWbuf, act, AB1, 1.f / 3.f, N1C);
        gather_kernel<<<(int)(((size_t)N2C * 8 + 255) / 256), 256, 0, stream>>>(
            rp_r[2], cv_r[2], XWbuf, act, AB2, 0.5f, N2C);
    }

    hipMemsetAsync(sums, 0, (size_t)(NGC * D + NGC) * sizeof(float), stream);
    {
        int groups = (N1C + 511) / 512;
        int blocks = (groups + 7) / 8;
        pool_kernel<<<blocks, 256, 0, stream>>>(act + (size_t)AB1 * 32, batch1, sums, cnt, N1C);
    }
    head_kernel<<<1, 128, 0, stream>>>(sums, cnt, mlp1_w, mlp1_b, mlp2_w, mlp2_b, out);
}

// Round 8
// 2954.959 us; speedup vs baseline: 2.4835x; 1.3398x over previous
//
#include <hip/hip_runtime.h>
#include <hip/hip_fp16.h>

#define N0C 200000
#define N1C 600000
#define N2C 400000
#define NRC (N0C + N1C + N2C)
#define NGC 128
#define D 32
#define SCAN_TILE 2048
#define CHUNK_EDGES 16384
#define NBUK_MAX 1184
#define LDSE 12288   // max edges per bucket for LDS sort (96 KB)

// act buffer row bases (rank-concatenated)
#define AB0 0
#define AB1 N0C
#define AB2 (N0C + N1C)

typedef __attribute__((ext_vector_type(8))) _Float16 half8;
typedef __attribute__((ext_vector_type(4))) float f32x4;

// ---------- scan helpers (for (bucket,chunk) histogram table) ----------
__global__ void scan_phase1(const int* __restrict__ counts, int* __restrict__ bsums, int n) {
    __shared__ int sd[256];
    int base = blockIdx.x * SCAN_TILE;
    int s = 0;
    for (int i = threadIdx.x; i < SCAN_TILE; i += 256) {
        int idx = base + i;
        s += (idx < n) ? counts[idx] : 0;
    }
    sd[threadIdx.x] = s;
    __syncthreads();
    for (int o = 128; o > 0; o >>= 1) {
        if (threadIdx.x < o) sd[threadIdx.x] += sd[threadIdx.x + o];
        __syncthreads();
    }
    if (threadIdx.x == 0) bsums[blockIdx.x] = sd[0];
}

__global__ void scan_phase2(int* __restrict__ bsums, int nb) {
    __shared__ int sd[1024];
    for (int i = threadIdx.x; i < nb; i += 256) sd[i] = bsums[i];
    __syncthreads();
    if (threadIdx.x == 0) {
        int acc = 0;
        for (int i = 0; i < nb; ++i) { int v = sd[i]; sd[i] = acc; acc += v; }
        bsums[nb] = acc;
    }
    __syncthreads();
    for (int i = threadIdx.x; i < nb; i += 256) bsums[i] = sd[i];
}

__global__ void scan_phase3(const int* __restrict__ counts, const int* __restrict__ bsums,
                            int* __restrict__ outscan, int n) {
    __shared__ int sd[256];
    int base = blockIdx.x * SCAN_TILE + threadIdx.x * 8;
    int v[8];
    int s = 0;
#pragma unroll
    for (int u = 0; u < 8; ++u) {
        int idx = base + u;
        int c = (idx < n) ? counts[idx] : 0;
        v[u] = s;
        s += c;
    }
    sd[threadIdx.x] = s;
    __syncthreads();
    if (threadIdx.x == 0) {
        int acc = bsums[blockIdx.x];
        for (int i = 0; i < 256; ++i) { int q = sd[i]; sd[i] = acc; acc += q; }
    }
    __syncthreads();
    int off = sd[threadIdx.x];
#pragma unroll
    for (int u = 0; u < 8; ++u) {
        int idx = base + u;
        if (idx < n) outscan[idx] = off + v[u];
    }
}

__global__ void set_total_kernel(int* __restrict__ dst, const int* __restrict__ src) {
    *dst = *src;
}

// ---------- binned build phase 1: per-chunk bucket histogram (transposed) ----------
__global__ __launch_bounds__(256) void bhist_kernel(const int* __restrict__ rows, int nnz,
                                                    int shift, int nbuk, int ncht, int chunk0,
                                                    int* __restrict__ HT) {
    __shared__ int h[NBUK_MAX];
    for (int i = threadIdx.x; i < nbuk; i += 256) h[i] = 0;
    __syncthreads();
    int base = blockIdx.x * CHUNK_EDGES;
    for (int i = threadIdx.x; i < CHUNK_EDGES; i += 256) {
        int e = base + i;
        if (e < nnz) atomicAdd(&h[rows[e] >> shift], 1);
    }
    __syncthreads();
    int c = chunk0 + blockIdx.x;
    for (int b = threadIdx.x; b < nbuk; b += 256) HT[b * ncht + c] = h[b];
}

// ---------- binned build phase 2: append into exclusive (bucket,chunk) stage ranges ----------
__global__ __launch_bounds__(256) void bin_kernel(const int* __restrict__ rows,
                                                  const int* __restrict__ cols,
                                                  const float* __restrict__ vals, int nnz,
                                                  int shift, int nbuk, int ncht, int chunk0,
                                                  int colbase, const int* __restrict__ HS,
                                                  int2* __restrict__ stage) {
    __shared__ int cur[NBUK_MAX];
    int c = chunk0 + blockIdx.x;
    for (int b = threadIdx.x; b < nbuk; b += 256) cur[b] = HS[b * ncht + c];
    __syncthreads();
    int base = blockIdx.x * CHUNK_EDGES;
    for (int i = threadIdx.x; i < CHUNK_EDGES; i += 256) {
        int e = base + i;
        if (e < nnz) {
            int r = rows[e];
            int b = r >> shift;
            int pos = atomicAdd(&cur[b], 1);
            int rl = r - (b << shift);
            stage[pos] = make_int2((rl << 22) | (cols[e] + colbase), __float_as_int(vals[e]));
        }
    }
}

__global__ void extract_b_kernel(const int* __restrict__ HS, int ncht, int nbuk, int total,
                                 int* __restrict__ B) {
    int b = blockIdx.x * blockDim.x + threadIdx.x;
    if (b < nbuk) B[b] = HS[b * ncht];
    if (b == nbuk) B[b] = total;
}

// ---------- binned build phase 3: per-bucket LDS counting sort -> rowptr + sequential cv ----------
__global__ __launch_bounds__(256) void binsort_kernel(const int2* __restrict__ stage,
                                                      const int* __restrict__ B, int shift,
                                                      int* __restrict__ rowptr,
                                                      int2* __restrict__ cv, int nrows) {
    __shared__ int hcnt[512], sa[512], sb[512], rcur[512];
    __shared__ int2 buf[LDSE];
    int b = blockIdx.x;
    int s0 = B[b], s1 = B[b + 1];
    int cnt = s1 - s0;
    int nr = 1 << shift;          // rows per bucket (256 or 512, power of two)
    int rb = b << shift;
    for (int i = threadIdx.x; i < nr; i += 256) hcnt[i] = 0;
    __syncthreads();
    // pass 1: row histogram
    for (int i = s0 + threadIdx.x; i < s1; i += 256)
        atomicAdd(&hcnt[(unsigned)stage[i].x >> 22], 1);
    __syncthreads();
    // inclusive Hillis-Steele scan of hcnt (nr <= 512)
    for (int i = threadIdx.x; i < nr; i += 256) sa[i] = hcnt[i];
    __syncthreads();
    int* curp = sa; int* nxtp = sb;
    for (int off = 1; off < nr; off <<= 1) {
        for (int i = threadIdx.x; i < nr; i += 256)
            nxtp[i] = (i >= off) ? curp[i - off] + curp[i] : curp[i];
        __syncthreads();
        int* t = curp; curp = nxtp; nxtp = t;
    }
    // exclusive offsets + rowptr
    for (int i = threadIdx.x; i < nr; i += 256) {
        int excl = curp[i] - hcnt[i];
        rcur[i] = excl;
        int row = rb + i;
        if (row < nrows) rowptr[row] = s0 + excl;
    }
    __syncthreads();
    if (cnt <= LDSE) {
        // pass 2: scatter into LDS buffer
        for (int i = s0 + threadIdx.x; i < s1; i += 256) {
            int2 e = stage[i];
            int rl = (unsigned)e.x >> 22;
            int pos = atomicAdd(&rcur[rl], 1);
            buf[pos] = make_int2(e.x & 0x3FFFFF, e.y);
        }
        __syncthreads();
        // pass 3: coalesced sequential write
        for (int i = threadIdx.x; i < cnt; i += 256)
            cv[s0 + i] = buf[i];
    } else {
        // statistical never-path: direct global scatter
        for (int i = s0 + threadIdx.x; i < s1; i += 256) {
            int2 e = stage[i];
            int rl = (unsigned)e.x >> 22;
            int pos = atomicAdd(&rcur[rl], 1);
            cv[s0 + pos] = make_int2(e.x & 0x3FFFFF, e.y);
        }
    }
}

// ---------- fused MFMA projection: for NM mats sharing one source ----------
// A frag (16x32 fp16): lane l -> row (l&15), k = (l>>4)*8 + r  (contiguous 16B)
// B frag (32x16 fp16): lane l -> col (l&15), k = (l>>4)*8 + r
// D frag (16x16 f32):  lane l -> col (l&15), row = (l>>4)*4 + r
template <int DIN, int NM, bool F32>
__global__ __launch_bounds__(256) void xw_fused_kernel(
    const void* __restrict__ xsrc,
    const float* __restrict__ Wa, const float* __restrict__ Wb, const float* __restrict__ Wc,
    __half* __restrict__ oa, __half* __restrict__ ob, __half* __restrict__ oc, int n) {
    int wave = (blockIdx.x * 256 + threadIdx.x) >> 6;
    int lane = threadIdx.x & 63;
    int nwaves = (gridDim.x * 256) >> 6;
    int li = lane & 15;
    int lk = lane >> 4;
    const float* Ws[3] = { Wa, Wb, Wc };
    __half* Os[3] = { oa, ob, oc };
    half8 bfrag[NM][2][DIN / 32];
#pragma unroll
    for (int m = 0; m < NM; ++m)
#pragma unroll
        for (int ct = 0; ct < 2; ++ct)
#pragma unroll
            for (int ks = 0; ks < DIN / 32; ++ks)
#pragma unroll
                for (int r = 0; r < 8; ++r) {
                    int k = ks * 32 + lk * 8 + r;
                    int j = ct * 16 + li;
                    bfrag[m][ct][ks][r] = (_Float16)Ws[m][k * 32 + j];
                }
    int ntiles = (n + 15) >> 4;
    for (int t = wave; t < ntiles; t += nwaves) {
        int rbase = t << 4;
        int arow = rbase + li;
        int arowc = (arow < n) ? arow : (n - 1);
        half8 afrag[DIN / 32];
#pragma unroll
        for (int ks = 0; ks < DIN / 32; ++ks) {
            if (F32) {
                const float* p = (const float*)xsrc + (size_t)arowc * DIN + ks * 32 + lk * 8;
                float4 u = *(const float4*)p;
                float4 v = *(const float4*)(p + 4);
                afrag[ks] = (half8){ (_Float16)u.x, (_Float16)u.y, (_Float16)u.z, (_Float16)u.w,
                                     (_Float16)v.x, (_Float16)v.y, (_Float16)v.z, (_Float16)v.w };
            } else {
                afrag[ks] = *(const half8*)((const __half*)xsrc + (size_t)arowc * DIN +
                                            ks * 32 + lk * 8);
            }
        }
#pragma unroll
        for (int m = 0; m < NM; ++m) {
#pragma unroll
            for (int ct = 0; ct < 2; ++ct) {
                f32x4 acc = { 0.f, 0.f, 0.f, 0.f };
#pragma unroll
                for (int ks = 0; ks < DIN / 32; ++ks)
                    acc = __builtin_amdgcn_mfma_f32_16x16x32_f16(afrag[ks], bfrag[m][ct][ks],
                                                                 acc, 0, 0, 0);
#pragma unroll
                for (int r = 0; r < 4; ++r) {
                    int row = rbase + lk * 4 + r;
                    if (row < n)
                        Os[m][(size_t)row * 32 + ct * 16 + li] = __float2half(acc[r]);
                }
            }
        }
    }
}

// ---------- pure gather: 8 lanes per row, half4 per lane ----------
__global__ __launch_bounds__(256, 8) void gather_kernel(
    const int* __restrict__ rp, const int2* __restrict__ cv,
    const __half* __restrict__ XW, __half* __restrict__ act,
    int rowbase, float scale, int n) {
    int g = (blockIdx.x * 256 + threadIdx.x) >> 3;
    int j = threadIdx.x & 7;
    if (g >= n) return;
    int ks = rp[g], ke = rp[g + 1];
    float s0 = 0.f, s1 = 0.f, s2 = 0.f, s3 = 0.f;
    for (int k = ks; k < ke; k += 8) {
        int2 e[8];
#pragma unroll
        for (int u = 0; u < 8; ++u) {
            int kk = k + u;
            e[u] = cv[(kk < ke) ? kk : (ke - 1)];
        }
        uint2 q[8];
#pragma unroll
        for (int u = 0; u < 8; ++u)
            q[u] = *(const uint2*)(XW + (size_t)e[u].x * 32 + j * 4);
#pragma unroll
        for (int u = 0; u < 8; ++u) {
            float v = (k + u < ke) ? __int_as_float(e[u].y) : 0.f;
            __half2 h01 = *(__half2*)&q[u].x;
            __half2 h23 = *(__half2*)&q[u].y;
            float2 f01 = __half22float2(h01);
            float2 f23 = __half22float2(h23);
            s0 = fmaf(v, f01.x, s0);
            s1 = fmaf(v, f01.y, s1);
            s2 = fmaf(v, f23.x, s2);
            s3 = fmaf(v, f23.y, s3);
        }
    }
    __half2 o01 = __floats2half2_rn(fmaxf(s0, 0.f) * scale, fmaxf(s1, 0.f) * scale);
    __half2 o23 = __floats2half2_rn(fmaxf(s2, 0.f) * scale, fmaxf(s3, 0.f) * scale);
    uint2 ov;
    ov.x = *(unsigned*)&o01;
    ov.y = *(unsigned*)&o23;
    *(uint2*)(act + (size_t)(rowbase + g) * 32 + j * 4) = ov;
}

// ---------- pooling (batch sorted) ----------
__global__ void pool_kernel(const __half* __restrict__ x1, const int* __restrict__ batch,
                            float* __restrict__ sums, float* __restrict__ cnt, int n) {
    const int RPG = 512;
    int j = threadIdx.x & 31;
    int s = threadIdx.x >> 5;
    long long start = ((long long)blockIdx.x * 8 + s) * RPG;
    if (start >= n) return;
    long long end = start + RPG;
    if (end > n) end = n;
    int curg = batch[start];
    float a = 0.f, c = 0.f;
    for (long long r = start; r < end; ++r) {
        int g = batch[r];
        if (g != curg) {
            atomicAdd(&sums[(size_t)curg * D + j], a);
            if (j == 0) atomicAdd(&cnt[curg], c);
            a = 0.f; c = 0.f; curg = g;
        }
        a += fabsf(__half2float(x1[(size_t)r * D + j]));
        c += 1.f;
    }
    atomicAdd(&sums[(size_t)curg * D + j], a);
    if (j == 0) atomicAdd(&cnt[curg], c);
}

// ---------- head ----------
__global__ void head_kernel(const float* __restrict__ sums, const float* __restrict__ cnt,
                            const float* __restrict__ w1, const float* __restrict__ b1,
                            const float* __restrict__ w2, const float* __restrict__ b2,
                            float* __restrict__ out) {
    __shared__ float W1s[D * D], W2s[D * 10], B1s[D], B2s[10];
    int tid = threadIdx.x;
    for (int i = tid; i < D * D; i += blockDim.x) W1s[i] = w1[i];
    for (int i = tid; i < D * 10; i += blockDim.x) W2s[i] = w2[i];
    if (tid < D) B1s[tid] = b1[tid];
    if (tid < 10) B2s[tid] = b2[tid];
    __syncthreads();
    int g = tid;
    if (g >= NGC) return;
    float invc = 1.f / fmaxf(cnt[g], 1.f);
    float p[D];
#pragma unroll
    for (int k = 0; k < D; ++k) p[k] = sums[(size_t)g * D + k] * invc;
    float h[D];
#pragma unroll
    for (int j = 0; j < D; ++j) {
        float s = B1s[j];
#pragma unroll
        for (int k = 0; k < D; ++k) s = fmaf(p[k], W1s[k * D + j], s);
        h[j] = fmaxf(s, 0.f);
    }
    float l[10];
    float m = -1e30f;
#pragma unroll
    for (int o = 0; o < 10; ++o) {
        float s = B2s[o];
#pragma unroll
        for (int k = 0; k < D; ++k) s = fmaf(h[k], W2s[k * 10 + o], s);
        l[o] = s;
        m = fmaxf(m, s);
    }
    float den = 0.f;
#pragma unroll
    for (int o = 0; o < 10; ++o) { l[o] = expf(l[o] - m); den += l[o]; }
    float inv = 1.f / den;
#pragma unroll
    for (int o = 0; o < 10; ++o) out[g * 10 + o] = l[o] * inv;
}

extern "C" void kernel_launch(void* const* d_in, const int* in_sizes, int n_in,
                              void* d_out, int out_size, void* d_ws, size_t ws_size,
                              hipStream_t stream) {
    const float* X0 = (const float*)d_in[0];
    const float* X1 = (const float*)d_in[1];
    const float* X2 = (const float*)d_in[2];
    // mats: 0=L0,1=L1,2=L2,3=B2D3,4=D2B1TD1inv,5=D1invB1,6=B2TD2inv
    const int* spr[7]; const int* spc[7]; const float* spv[7]; int spn[7];
    for (int m = 0; m < 7; ++m) {
        spr[m] = (const int*)d_in[3 + m * 3];
        spc[m] = (const int*)d_in[4 + m * 3];
        spv[m] = (const float*)d_in[5 + m * 3];
        spn[m] = in_sizes[3 + m * 3];
    }
    const int* batch1 = (const int*)d_in[24];
    const float* W1 = (const float*)d_in[25];
    const float* W234 = (const float*)d_in[26];
    const float* mlp1_w = (const float*)d_in[27];
    const float* mlp1_b = (const float*)d_in[28];
    const float* mlp2_w = (const float*)d_in[29];
    const float* mlp2_b = (const float*)d_in[30];
    float* out = (float*)d_out;

    // per-mat: src rows, W index
    const int srcrows_mat[7] = { N0C, N1C, N2C, N2C, N0C, N1C, N1C };
    int XB[7];  // XWbuf slot bases
    {
        int acc = 0;
        for (int m = 0; m < 7; ++m) { XB[m] = acc; acc += srcrows_mat[m]; }
    }
    const int XWROWS = 3000000;

    // rank CSRs: rank0 <- {L0, D1invB1}; rank1 <- {D2B1TD1inv, L1, B2D3}; rank2 <- {B2TD2inv, L2}
    struct RankDef { int nrows; int nmats; int mats[3]; int shift; };
    const RankDef rdefs[3] = {
        { N0C, 2, { 0, 5, -1 }, 8 },
        { N1C, 3, { 4, 1, 3 }, 9 },
        { N2C, 2, { 6, 2, -1 }, 9 },
    };

    // ---- workspace carve ----
    char* wp = (char*)d_ws;
    __half* act = (__half*)wp;             wp += (size_t)NRC * 32 * sizeof(__half);   // 76.8MB
    __half* XWbuf = (__half*)wp;           wp += (size_t)XWROWS * 32 * sizeof(__half);// 192MB
    size_t total_nnz = 0;
    for (int m = 0; m < 7; ++m) total_nnz += (size_t)spn[m];
    int2* cv_base = (int2*)wp;             wp += total_nnz * sizeof(int2);            // 134.4MB
    int* rowptr_base = (int*)wp;           wp += (size_t)(NRC + 3) * sizeof(int);
    int* HT = (int*)wp;                    wp += (size_t)1000000 * sizeof(int);
    int* HS = (int*)wp;                    wp += (size_t)1000000 * sizeof(int);
    int* Bb = (int*)wp;                    wp += (size_t)(NBUK_MAX + 1) * sizeof(int);
    int* bsums = (int*)wp;                 wp += 1040 * sizeof(int);
    float* sums = (float*)wp;              wp += (size_t)NGC * D * sizeof(float);
    float* cnt = (float*)wp;               wp += (size_t)NGC * sizeof(float);

    // stage aliases XWbuf (build finishes before first xw write)
    int2* stage = (int2*)XWbuf;

    // ---- build 3 merged rank CSRs via binned sort ----
    int* rp_r[3]; int2* cv_r[3];
    {
        size_t rpoff = 0, cvoff = 0;
        for (int r = 0; r < 3; ++r) {
            const RankDef& rd = rdefs[r];
            int nr = rd.nrows;
            int shift = rd.shift;
            int nbuk = (nr + (1 << shift) - 1) >> shift;
            rp_r[r] = rowptr_base + rpoff; rpoff += (size_t)nr + 1;
            cv_r[r] = cv_base + cvoff;
            int rank_nnz = 0;
            int ncht = 0;
            int chunk0_mat[3] = { 0, 0, 0 };
            for (int i = 0; i < rd.nmats; ++i) {
                chunk0_mat[i] = ncht;
                ncht += (spn[rd.mats[i]] + CHUNK_EDGES - 1) / CHUNK_EDGES;
                rank_nnz += spn[rd.mats[i]];
            }

            // (bucket, chunk) histogram -> scan -> stage offsets
            for (int i = 0; i < rd.nmats; ++i) {
                int m = rd.mats[i];
                int gch = (spn[m] + CHUNK_EDGES - 1) / CHUNK_EDGES;
                bhist_kernel<<<gch, 256, 0, stream>>>(spr[m], spn[m], shift, nbuk, ncht,
                                                      chunk0_mat[i], HT);
            }
            int nht = nbuk * ncht;
            int nbh = (nht + SCAN_TILE - 1) / SCAN_TILE;
            scan_phase1<<<nbh, 256, 0, stream>>>(HT, bsums, nht);
            scan_phase2<<<1, 256, 0, stream>>>(bsums, nbh);
            scan_phase3<<<nbh, 256, 0, stream>>>(HT, bsums, HS, nht);
            extract_b_kernel<<<(nbuk + 256) / 256, 256, 0, stream>>>(HS, ncht, nbuk,
                                                                     rank_nnz, Bb);

            // bin into stage, then per-bucket LDS sort -> rowptr + cv
            for (int i = 0; i < rd.nmats; ++i) {
                int m = rd.mats[i];
                int gch = (spn[m] + CHUNK_EDGES - 1) / CHUNK_EDGES;
                bin_kernel<<<gch, 256, 0, stream>>>(spr[m], spc[m], spv[m], spn[m], shift,
                                                    nbuk, ncht, chunk0_mat[i], XB[m], HS, stage);
            }
            binsort_kernel<<<nbuk, 256, 0, stream>>>(stage, Bb, shift, rp_r[r], cv_r[r], nr);
            set_total_kernel<<<1, 1, 0, stream>>>(rp_r[r] + nr, Bb + nbuk);

            cvoff += (size_t)rank_nnz;
        }
    }

    // ---- 4 layers: 3 fused projections + 3 gathers each ----
    for (int l = 0; l < 4; ++l) {
        const float* Wl = (l == 0) ? W1 : W234 + (size_t)(l - 1) * 7 * 32 * 32;
        const size_t wst = (l == 0) ? (size_t)64 * 32 : (size_t)32 * 32;
#define WPK(k) (Wl + (size_t)(k) * wst)
#define SLOT(m) (XWbuf + (size_t)XB[m] * 32)
        if (l == 0) {
            // src x0 -> mats {0 (wk0), 4 (wk1)}; x1 -> {1 (wk2), 5 (wk3), 6 (wk4)}; x2 -> {2 (wk6), 3 (wk5)}
            xw_fused_kernel<64, 2, true><<<2048, 256, 0, stream>>>(
                X0, WPK(0), WPK(1), nullptr, SLOT(0), SLOT(4), nullptr, N0C);
            xw_fused_kernel<64, 3, true><<<2048, 256, 0, stream>>>(
                X1, WPK(2), WPK(3), WPK(4), SLOT(1), SLOT(5), SLOT(6), N1C);
            xw_fused_kernel<64, 2, true><<<2048, 256, 0, stream>>>(
                X2, WPK(6), WPK(5), nullptr, SLOT(2), SLOT(3), nullptr, N2C);
        } else {
            xw_fused_kernel<32, 2, false><<<2048, 256, 0, stream>>>(
                act + (size_t)AB0 * 32, WPK(0), WPK(1), nullptr, SLOT(0), SLOT(4), nullptr, N0C);
            xw_fused_kernel<32, 3, false><<<2048, 256, 0, stream>>>(
                act + (size_t)AB1 * 32, WPK(2), WPK(3), WPK(4), SLOT(1), SLOT(5), SLOT(6), N1C);
            xw_fused_kernel<32, 2, false><<<2048, 256, 0, stream>>>(
                act + (size_t)AB2 * 32, WPK(6), WPK(5), nullptr, SLOT(2), SLOT(3), nullptr, N2C);
        }
#undef WPK
#undef SLOT
        gather_kernel<<<(int)(((size_t)N0C * 8 + 255) / 256), 256, 0, stream>>>(
            rp_r[0], cv_r[0], XWbuf, act, AB0, 0.5f, N0C);
        gather_kernel<<<(int)(((size_t)N1C * 8 + 255) / 256), 256, 0, stream>>>(
            rp_r[1], cv_r[1], XWbuf, act, AB1, 1.f / 3.f, N1C);
        gather_kernel<<<(int)(((size_t)N2C * 8 + 255) / 256), 256, 0, stream>>>(
            rp_r[2], cv_r[2], XWbuf, act, AB2, 0.5f, N2C);
    }

    hipMemsetAsync(sums, 0, (size_t)(NGC * D + NGC) * sizeof(float), stream);
    {
        int groups = (N1C + 511) / 512;
        int blocks = (groups + 7) / 8;
        pool_kernel<<<blocks, 256, 0, stream>>>(act + (size_t)AB1 * 32, batch1, sums, cnt, N1C);
    }
    head_kernel<<<1, 128, 0, stream>>>(sums, cnt, mlp1_w, mlp1_b, mlp2_w, mlp2_b, out);
}

// Round 9
// 2575.445 us; speedup vs baseline: 2.8495x; 1.1474x over previous
//
#include <hip/hip_runtime.h>
#include <hip/hip_fp16.h>

#define N0C 200000
#define N1C 600000
#define N2C 400000
#define NRC (N0C + N1C + N2C)
#define NGC 128
#define D 32
#define SCAN_TILE 2048
#define CHUNK_EDGES 16384
#define NBUK_MAX 1184
#define LDSE 12288   // max edges per bucket for LDS sort (96 KB)

// act buffer row bases (rank-concatenated)
#define AB0 0
#define AB1 N0C
#define AB2 (N0C + N1C)

typedef __attribute__((ext_vector_type(8))) _Float16 half8;
typedef __attribute__((ext_vector_type(4))) float f32x4;

// ---------- scan helpers (for (bucket,chunk) histogram table) ----------
__global__ void scan_phase1(const int* __restrict__ counts, int* __restrict__ bsums, int n) {
    __shared__ int sd[256];
    int base = blockIdx.x * SCAN_TILE;
    int s = 0;
    for (int i = threadIdx.x; i < SCAN_TILE; i += 256) {
        int idx = base + i;
        s += (idx < n) ? counts[idx] : 0;
    }
    sd[threadIdx.x] = s;
    __syncthreads();
    for (int o = 128; o > 0; o >>= 1) {
        if (threadIdx.x < o) sd[threadIdx.x] += sd[threadIdx.x + o];
        __syncthreads();
    }
    if (threadIdx.x == 0) bsums[blockIdx.x] = sd[0];
}

__global__ void scan_phase2(int* __restrict__ bsums, int nb) {
    __shared__ int sd[1024];
    for (int i = threadIdx.x; i < nb; i += 256) sd[i] = bsums[i];
    __syncthreads();
    if (threadIdx.x == 0) {
        int acc = 0;
        for (int i = 0; i < nb; ++i) { int v = sd[i]; sd[i] = acc; acc += v; }
        bsums[nb] = acc;
    }
    __syncthreads();
    for (int i = threadIdx.x; i < nb; i += 256) bsums[i] = sd[i];
}

__global__ void scan_phase3(const int* __restrict__ counts, const int* __restrict__ bsums,
                            int* __restrict__ outscan, int n) {
    __shared__ int sd[256];
    int base = blockIdx.x * SCAN_TILE + threadIdx.x * 8;
    int v[8];
    int s = 0;
#pragma unroll
    for (int u = 0; u < 8; ++u) {
        int idx = base + u;
        int c = (idx < n) ? counts[idx] : 0;
        v[u] = s;
        s += c;
    }
    sd[threadIdx.x] = s;
    __syncthreads();
    if (threadIdx.x == 0) {
        int acc = bsums[blockIdx.x];
        for (int i = 0; i < 256; ++i) { int q = sd[i]; sd[i] = acc; acc += q; }
    }
    __syncthreads();
    int off = sd[threadIdx.x];
#pragma unroll
    for (int u = 0; u < 8; ++u) {
        int idx = base + u;
        if (idx < n) outscan[idx] = off + v[u];
    }
}

__global__ void set_total_kernel(int* __restrict__ dst, const int* __restrict__ src) {
    *dst = *src;
}

// ---------- binned build phase 1: per-chunk bucket histogram (transposed) ----------
__global__ __launch_bounds__(256) void bhist_kernel(const int* __restrict__ rows, int nnz,
                                                    int shift, int nbuk, int ncht, int chunk0,
                                                    int* __restrict__ HT) {
    __shared__ int h[NBUK_MAX];
    for (int i = threadIdx.x; i < nbuk; i += 256) h[i] = 0;
    __syncthreads();
    int base = blockIdx.x * CHUNK_EDGES;
    for (int i = threadIdx.x; i < CHUNK_EDGES; i += 256) {
        int e = base + i;
        if (e < nnz) atomicAdd(&h[rows[e] >> shift], 1);
    }
    __syncthreads();
    int c = chunk0 + blockIdx.x;
    for (int b = threadIdx.x; b < nbuk; b += 256) HT[b * ncht + c] = h[b];
}

// ---------- binned build phase 2: append into exclusive (bucket,chunk) stage ranges ----------
__global__ __launch_bounds__(256) void bin_kernel(const int* __restrict__ rows,
                                                  const int* __restrict__ cols,
                                                  const float* __restrict__ vals, int nnz,
                                                  int shift, int nbuk, int ncht, int chunk0,
                                                  int colbase, const int* __restrict__ HS,
                                                  int2* __restrict__ stage) {
    __shared__ int cur[NBUK_MAX];
    int c = chunk0 + blockIdx.x;
    for (int b = threadIdx.x; b < nbuk; b += 256) cur[b] = HS[b * ncht + c];
    __syncthreads();
    int base = blockIdx.x * CHUNK_EDGES;
    for (int i = threadIdx.x; i < CHUNK_EDGES; i += 256) {
        int e = base + i;
        if (e < nnz) {
            int r = rows[e];
            int b = r >> shift;
            int pos = atomicAdd(&cur[b], 1);
            int rl = r - (b << shift);
            stage[pos] = make_int2((rl << 22) | (cols[e] + colbase), __float_as_int(vals[e]));
        }
    }
}

__global__ void extract_b_kernel(const int* __restrict__ HS, int ncht, int nbuk, int total,
                                 int* __restrict__ B) {
    int b = blockIdx.x * blockDim.x + threadIdx.x;
    if (b < nbuk) B[b] = HS[b * ncht];
    if (b == nbuk) B[b] = total;
}

// ---------- binned build phase 3: per-bucket LDS counting sort -> rowptr + sequential cv ----------
__global__ __launch_bounds__(256) void binsort_kernel(const int2* __restrict__ stage,
                                                      const int* __restrict__ B, int shift,
                                                      int* __restrict__ rowptr,
                                                      int2* __restrict__ cv, int nrows) {
    __shared__ int hcnt[512], sa[512], sb[512], rcur[512];
    __shared__ int2 buf[LDSE];
    int b = blockIdx.x;
    int s0 = B[b], s1 = B[b + 1];
    int cnt = s1 - s0;
    int nr = 1 << shift;
    int rb = b << shift;
    for (int i = threadIdx.x; i < nr; i += 256) hcnt[i] = 0;
    __syncthreads();
    for (int i = s0 + threadIdx.x; i < s1; i += 256)
        atomicAdd(&hcnt[(unsigned)stage[i].x >> 22], 1);
    __syncthreads();
    for (int i = threadIdx.x; i < nr; i += 256) sa[i] = hcnt[i];
    __syncthreads();
    int* curp = sa; int* nxtp = sb;
    for (int off = 1; off < nr; off <<= 1) {
        for (int i = threadIdx.x; i < nr; i += 256)
            nxtp[i] = (i >= off) ? curp[i - off] + curp[i] : curp[i];
        __syncthreads();
        int* t = curp; curp = nxtp; nxtp = t;
    }
    for (int i = threadIdx.x; i < nr; i += 256) {
        int excl = curp[i] - hcnt[i];
        rcur[i] = excl;
        int row = rb + i;
        if (row < nrows) rowptr[row] = s0 + excl;
    }
    __syncthreads();
    if (cnt <= LDSE) {
        for (int i = s0 + threadIdx.x; i < s1; i += 256) {
            int2 e = stage[i];
            int rl = (unsigned)e.x >> 22;
            int pos = atomicAdd(&rcur[rl], 1);
            buf[pos] = make_int2(e.x & 0x3FFFFF, e.y);
        }
        __syncthreads();
        for (int i = threadIdx.x; i < cnt; i += 256)
            cv[s0 + i] = buf[i];
    } else {
        for (int i = s0 + threadIdx.x; i < s1; i += 256) {
            int2 e = stage[i];
            int rl = (unsigned)e.x >> 22;
            int pos = atomicAdd(&rcur[rl], 1);
            cv[s0 + pos] = make_int2(e.x & 0x3FFFFF, e.y);
        }
    }
}

// ---------- fused MFMA projection: for NM mats sharing one source ----------
template <int DIN, int NM, bool F32>
__global__ __launch_bounds__(256) void xw_fused_kernel(
    const void* __restrict__ xsrc,
    const float* __restrict__ Wa, const float* __restrict__ Wb, const float* __restrict__ Wc,
    __half* __restrict__ oa, __half* __restrict__ ob, __half* __restrict__ oc, int n) {
    int wave = (blockIdx.x * 256 + threadIdx.x) >> 6;
    int lane = threadIdx.x & 63;
    int nwaves = (gridDim.x * 256) >> 6;
    int li = lane & 15;
    int lk = lane >> 4;
    const float* Ws[3] = { Wa, Wb, Wc };
    __half* Os[3] = { oa, ob, oc };
    half8 bfrag[NM][2][DIN / 32];
#pragma unroll
    for (int m = 0; m < NM; ++m)
#pragma unroll
        for (int ct = 0; ct < 2; ++ct)
#pragma unroll
            for (int ks = 0; ks < DIN / 32; ++ks)
#pragma unroll
                for (int r = 0; r < 8; ++r) {
                    int k = ks * 32 + lk * 8 + r;
                    int j = ct * 16 + li;
                    bfrag[m][ct][ks][r] = (_Float16)Ws[m][k * 32 + j];
                }
    int ntiles = (n + 15) >> 4;
    for (int t = wave; t < ntiles; t += nwaves) {
        int rbase = t << 4;
        int arow = rbase + li;
        int arowc = (arow < n) ? arow : (n - 1);
        half8 afrag[DIN / 32];
#pragma unroll
        for (int ks = 0; ks < DIN / 32; ++ks) {
            if (F32) {
                const float* p = (const float*)xsrc + (size_t)arowc * DIN + ks * 32 + lk * 8;
                float4 u = *(const float4*)p;
                float4 v = *(const float4*)(p + 4);
                afrag[ks] = (half8){ (_Float16)u.x, (_Float16)u.y, (_Float16)u.z, (_Float16)u.w,
                                     (_Float16)v.x, (_Float16)v.y, (_Float16)v.z, (_Float16)v.w };
            } else {
                afrag[ks] = *(const half8*)((const __half*)xsrc + (size_t)arowc * DIN +
                                            ks * 32 + lk * 8);
            }
        }
#pragma unroll
        for (int m = 0; m < NM; ++m) {
#pragma unroll
            for (int ct = 0; ct < 2; ++ct) {
                f32x4 acc = { 0.f, 0.f, 0.f, 0.f };
#pragma unroll
                for (int ks = 0; ks < DIN / 32; ++ks)
                    acc = __builtin_amdgcn_mfma_f32_16x16x32_f16(afrag[ks], bfrag[m][ct][ks],
                                                                 acc, 0, 0, 0);
#pragma unroll
                for (int r = 0; r < 4; ++r) {
                    int row = rbase + lk * 4 + r;
                    if (row < n)
                        Os[m][(size_t)row * 32 + ct * 16 + li] = __float2half(acc[r]);
                }
            }
        }
    }
}

// ---------- pure gather: 4 lanes per row, uint4 (16B) per lane ----------
__global__ __launch_bounds__(256) void gather_kernel(
    const int* __restrict__ rp, const int2* __restrict__ cv,
    const __half* __restrict__ XW, __half* __restrict__ act,
    int rowbase, float scale, int n) {
    int g = (blockIdx.x * 256 + threadIdx.x) >> 2;
    int j = threadIdx.x & 3;
    if (g >= n) return;
    int ks = rp[g], ke = rp[g + 1];
    float s[8] = { 0.f, 0.f, 0.f, 0.f, 0.f, 0.f, 0.f, 0.f };
    for (int k = ks; k < ke; k += 8) {
        int2 e[8];
#pragma unroll
        for (int u = 0; u < 8; ++u) {
            int kk = k + u;
            e[u] = cv[(kk < ke) ? kk : (ke - 1)];
        }
        uint4 q[8];
#pragma unroll
        for (int u = 0; u < 8; ++u)
            q[u] = *(const uint4*)(XW + (size_t)e[u].x * 32 + j * 8);
#pragma unroll
        for (int u = 0; u < 8; ++u) {
            float v = (k + u < ke) ? __int_as_float(e[u].y) : 0.f;
            const unsigned* qq = &q[u].x;
#pragma unroll
            for (int h = 0; h < 4; ++h) {
                __half2 h2 = *(__half2*)&qq[h];
                float2 f2 = __half22float2(h2);
                s[2 * h] = fmaf(v, f2.x, s[2 * h]);
                s[2 * h + 1] = fmaf(v, f2.y, s[2 * h + 1]);
            }
        }
    }
    uint4 ov;
    unsigned* op = &ov.x;
#pragma unroll
    for (int h = 0; h < 4; ++h) {
        __half2 o2 = __floats2half2_rn(fmaxf(s[2 * h], 0.f) * scale,
                                       fmaxf(s[2 * h + 1], 0.f) * scale);
        op[h] = *(unsigned*)&o2;
    }
    *(uint4*)(act + (size_t)(rowbase + g) * 32 + j * 8) = ov;
}

// ---------- pooling: per-graph binary search + block reduction ----------
#define BPG 4
__global__ __launch_bounds__(256) void pool_kernel(const __half* __restrict__ x1,
                                                   const int* __restrict__ batch,
                                                   float* __restrict__ sums,
                                                   float* __restrict__ cnt, int n) {
    __shared__ float red[256][8];
    int g = blockIdx.x / BPG;
    int p = blockIdx.x % BPG;
    // lower_bound
    int lo = 0, hi = n;
    while (lo < hi) { int mid = (lo + hi) >> 1; if (batch[mid] < g) lo = mid + 1; else hi = mid; }
    int s0 = lo;
    lo = s0; hi = n;
    while (lo < hi) { int mid = (lo + hi) >> 1; if (batch[mid] < g + 1) lo = mid + 1; else hi = mid; }
    int s1 = lo;
    int tid = threadIdx.x;
    int qr = tid & 3;       // 8-dim chunk
    int rt = tid >> 2;      // row lane [0,64)
    float acc[8] = { 0.f, 0.f, 0.f, 0.f, 0.f, 0.f, 0.f, 0.f };
    for (int r = s0 + p * 64 + rt; r < s1; r += BPG * 64) {
        half8 v = *(const half8*)(x1 + (size_t)r * 32 + qr * 8);
#pragma unroll
        for (int u = 0; u < 8; ++u) acc[u] += fabsf((float)v[u]);
    }
#pragma unroll
    for (int u = 0; u < 8; ++u) red[tid][u] = acc[u];
    __syncthreads();
    for (int off = 128; off >= 4; off >>= 1) {
        if (tid < off) {
#pragma unroll
            for (int u = 0; u < 8; ++u) red[tid][u] += red[tid + off][u];
        }
        __syncthreads();
    }
    if (tid < 4) {
#pragma unroll
        for (int u = 0; u < 8; ++u)
            atomicAdd(&sums[(size_t)g * D + tid * 8 + u], red[tid][u]);
    }
    if (p == 0 && tid == 0) cnt[g] = (float)(s1 - s0);
}

// ---------- head ----------
__global__ void head_kernel(const float* __restrict__ sums, const float* __restrict__ cnt,
                            const float* __restrict__ w1, const float* __restrict__ b1,
                            const float* __restrict__ w2, const float* __restrict__ b2,
                            float* __restrict__ out) {
    __shared__ float W1s[D * D], W2s[D * 10], B1s[D], B2s[10];
    int tid = threadIdx.x;
    for (int i = tid; i < D * D; i += blockDim.x) W1s[i] = w1[i];
    for (int i = tid; i < D * 10; i += blockDim.x) W2s[i] = w2[i];
    if (tid < D) B1s[tid] = b1[tid];
    if (tid < 10) B2s[tid] = b2[tid];
    __syncthreads();
    int g = tid;
    if (g >= NGC) return;
    float invc = 1.f / fmaxf(cnt[g], 1.f);
    float p[D];
#pragma unroll
    for (int k = 0; k < D; ++k) p[k] = sums[(size_t)g * D + k] * invc;
    float h[D];
#pragma unroll
    for (int j = 0; j < D; ++j) {
        float s = B1s[j];
#pragma unroll
        for (int k = 0; k < D; ++k) s = fmaf(p[k], W1s[k * D + j], s);
        h[j] = fmaxf(s, 0.f);
    }
    float l[10];
    float m = -1e30f;
#pragma unroll
    for (int o = 0; o < 10; ++o) {
        float s = B2s[o];
#pragma unroll
        for (int k = 0; k < D; ++k) s = fmaf(h[k], W2s[k * 10 + o], s);
        l[o] = s;
        m = fmaxf(m, s);
    }
    float den = 0.f;
#pragma unroll
    for (int o = 0; o < 10; ++o) { l[o] = expf(l[o] - m); den += l[o]; }
    float inv = 1.f / den;
#pragma unroll
    for (int o = 0; o < 10; ++o) out[g * 10 + o] = l[o] * inv;
}

extern "C" void kernel_launch(void* const* d_in, const int* in_sizes, int n_in,
                              void* d_out, int out_size, void* d_ws, size_t ws_size,
                              hipStream_t stream) {
    const float* X0 = (const float*)d_in[0];
    const float* X1 = (const float*)d_in[1];
    const float* X2 = (const float*)d_in[2];
    // mats: 0=L0,1=L1,2=L2,3=B2D3,4=D2B1TD1inv,5=D1invB1,6=B2TD2inv
    const int* spr[7]; const int* spc[7]; const float* spv[7]; int spn[7];
    for (int m = 0; m < 7; ++m) {
        spr[m] = (const int*)d_in[3 + m * 3];
        spc[m] = (const int*)d_in[4 + m * 3];
        spv[m] = (const float*)d_in[5 + m * 3];
        spn[m] = in_sizes[3 + m * 3];
    }
    const int* batch1 = (const int*)d_in[24];
    const float* W1 = (const float*)d_in[25];
    const float* W234 = (const float*)d_in[26];
    const float* mlp1_w = (const float*)d_in[27];
    const float* mlp1_b = (const float*)d_in[28];
    const float* mlp2_w = (const float*)d_in[29];
    const float* mlp2_b = (const float*)d_in[30];
    float* out = (float*)d_out;

    const int srcrows_mat[7] = { N0C, N1C, N2C, N2C, N0C, N1C, N1C };
    int XB[7];
    {
        int acc = 0;
        for (int m = 0; m < 7; ++m) { XB[m] = acc; acc += srcrows_mat[m]; }
    }
    const int XWROWS = 3000000;

    struct RankDef { int nrows; int nmats; int mats[3]; int shift; };
    const RankDef rdefs[3] = {
        { N0C, 2, { 0, 5, -1 }, 8 },
        { N1C, 3, { 4, 1, 3 }, 9 },
        { N2C, 2, { 6, 2, -1 }, 9 },
    };

    // ---- workspace carve ----
    char* wp = (char*)d_ws;
    __half* act = (__half*)wp;             wp += (size_t)NRC * 32 * sizeof(__half);
    __half* XWbuf = (__half*)wp;           wp += (size_t)XWROWS * 32 * sizeof(__half);
    size_t total_nnz = 0;
    for (int m = 0; m < 7; ++m) total_nnz += (size_t)spn[m];
    int2* cv_base = (int2*)wp;             wp += total_nnz * sizeof(int2);
    int* rowptr_base = (int*)wp;           wp += (size_t)(NRC + 3) * sizeof(int);
    int* HT = (int*)wp;                    wp += (size_t)1000000 * sizeof(int);
    int* HS = (int*)wp;                    wp += (size_t)1000000 * sizeof(int);
    int* Bb = (int*)wp;                    wp += (size_t)(NBUK_MAX + 1) * sizeof(int);
    int* bsums = (int*)wp;                 wp += 1040 * sizeof(int);
    float* sums = (float*)wp;              wp += (size_t)NGC * D * sizeof(float);
    float* cnt = (float*)wp;               wp += (size_t)NGC * sizeof(float);

    int2* stage = (int2*)XWbuf;

    // ---- build 3 merged rank CSRs via binned sort ----
    int* rp_r[3]; int2* cv_r[3];
    {
        size_t rpoff = 0, cvoff = 0;
        for (int r = 0; r < 3; ++r) {
            const RankDef& rd = rdefs[r];
            int nr = rd.nrows;
            int shift = rd.shift;
            int nbuk = (nr + (1 << shift) - 1) >> shift;
            rp_r[r] = rowptr_base + rpoff; rpoff += (size_t)nr + 1;
            cv_r[r] = cv_base + cvoff;
            int rank_nnz = 0;
            int ncht = 0;
            int chunk0_mat[3] = { 0, 0, 0 };
            for (int i = 0; i < rd.nmats; ++i) {
                chunk0_mat[i] = ncht;
                ncht += (spn[rd.mats[i]] + CHUNK_EDGES - 1) / CHUNK_EDGES;
                rank_nnz += spn[rd.mats[i]];
            }

            for (int i = 0; i < rd.nmats; ++i) {
                int m = rd.mats[i];
                int gch = (spn[m] + CHUNK_EDGES - 1) / CHUNK_EDGES;
                bhist_kernel<<<gch, 256, 0, stream>>>(spr[m], spn[m], shift, nbuk, ncht,
                                                      chunk0_mat[i], HT);
            }
            int nht = nbuk * ncht;
            int nbh = (nht + SCAN_TILE - 1) / SCAN_TILE;
            scan_phase1<<<nbh, 256, 0, stream>>>(HT, bsums, nht);
            scan_phase2<<<1, 256, 0, stream>>>(bsums, nbh);
            scan_phase3<<<nbh, 256, 0, stream>>>(HT, bsums, HS, nht);
            extract_b_kernel<<<(nbuk + 256) / 256, 256, 0, stream>>>(HS, ncht, nbuk,
                                                                     rank_nnz, Bb);

            for (int i = 0; i < rd.nmats; ++i) {
                int m = rd.mats[i];
                int gch = (spn[m] + CHUNK_EDGES - 1) / CHUNK_EDGES;
                bin_kernel<<<gch, 256, 0, stream>>>(spr[m], spc[m], spv[m], spn[m], shift,
                                                    nbuk, ncht, chunk0_mat[i], XB[m], HS, stage);
            }
            binsort_kernel<<<nbuk, 256, 0, stream>>>(stage, Bb, shift, rp_r[r], cv_r[r], nr);
            set_total_kernel<<<1, 1, 0, stream>>>(rp_r[r] + nr, Bb + nbuk);

            cvoff += (size_t)rank_nnz;
        }
    }

    // ---- 4 layers; layer 3 computes only what feeds the pooled x1 ----
    for (int l = 0; l < 4; ++l) {
        const float* Wl = (l == 0) ? W1 : W234 + (size_t)(l - 1) * 7 * 32 * 32;
        const size_t wst = (l == 0) ? (size_t)64 * 32 : (size_t)32 * 32;
#define WPK(k) (Wl + (size_t)(k) * wst)
#define SLOT(m) (XWbuf + (size_t)XB[m] * 32)
        if (l == 0) {
            xw_fused_kernel<64, 2, true><<<2048, 256, 0, stream>>>(
                X0, WPK(0), WPK(1), nullptr, SLOT(0), SLOT(4), nullptr, N0C);
            xw_fused_kernel<64, 3, true><<<2048, 256, 0, stream>>>(
                X1, WPK(2), WPK(3), WPK(4), SLOT(1), SLOT(5), SLOT(6), N1C);
            xw_fused_kernel<64, 2, true><<<2048, 256, 0, stream>>>(
                X2, WPK(6), WPK(5), nullptr, SLOT(2), SLOT(3), nullptr, N2C);
        } else if (l < 3) {
            xw_fused_kernel<32, 2, false><<<2048, 256, 0, stream>>>(
                act + (size_t)AB0 * 32, WPK(0), WPK(1), nullptr, SLOT(0), SLOT(4), nullptr, N0C);
            xw_fused_kernel<32, 3, false><<<2048, 256, 0, stream>>>(
                act + (size_t)AB1 * 32, WPK(2), WPK(3), WPK(4), SLOT(1), SLOT(5), SLOT(6), N1C);
            xw_fused_kernel<32, 2, false><<<2048, 256, 0, stream>>>(
                act + (size_t)AB2 * 32, WPK(6), WPK(5), nullptr, SLOT(2), SLOT(3), nullptr, N2C);
        } else {
            // only rank-1 inputs: slots 4 (x0·W1), 1 (x1·W2), 3 (x2·W5)
            xw_fused_kernel<32, 1, false><<<2048, 256, 0, stream>>>(
                act + (size_t)AB0 * 32, WPK(1), nullptr, nullptr, SLOT(4), nullptr, nullptr, N0C);
            xw_fused_kernel<32, 1, false><<<2048, 256, 0, stream>>>(
                act + (size_t)AB1 * 32, WPK(2), nullptr, nullptr, SLOT(1), nullptr, nullptr, N1C);
            xw_fused_kernel<32, 1, false><<<2048, 256, 0, stream>>>(
                act + (size_t)AB2 * 32, WPK(5), nullptr, nullptr, SLOT(3), nullptr, nullptr, N2C);
        }
#undef WPK
#undef SLOT
        if (l < 3) {
            gather_kernel<<<(int)(((size_t)N0C * 4 + 255) / 256), 256, 0, stream>>>(
                rp_r[0], cv_r[0], XWbuf, act, AB0, 0.5f, N0C);
            gather_kernel<<<(int)(((size_t)N1C * 4 + 255) / 256), 256, 0, stream>>>(
                rp_r[1], cv_r[1], XWbuf, act, AB1, 1.f / 3.f, N1C);
            gather_kernel<<<(int)(((size_t)N2C * 4 + 255) / 256), 256, 0, stream>>>(
                rp_r[2], cv_r[2], XWbuf, act, AB2, 0.5f, N2C);
        } else {
            gather_kernel<<<(int)(((size_t)N1C * 4 + 255) / 256), 256, 0, stream>>>(
                rp_r[1], cv_r[1], XWbuf, act, AB1, 1.f / 3.f, N1C);
        }
    }

    hipMemsetAsync(sums, 0, (size_t)(NGC * D + NGC) * sizeof(float), stream);
    pool_kernel<<<NGC * BPG, 256, 0, stream>>>(act + (size_t)AB1 * 32, batch1, sums, cnt, N1C);
    head_kernel<<<1, 128, 0, stream>>>(sums, cnt, mlp1_w, mlp1_b, mlp2_w, mlp2_b, out);
}